// Round 4
// baseline (176.998 us; speedup 1.0000x reference)
//
#include <hip/hip_runtime.h>
#include <hip/hip_fp16.h>
#include <stdint.h>

// MaskCrossAttention: B=4, LQ=LKV=1024, C=EMBED=768, NH=12, HD=64, SCALE=0.125
// Round 3: attn triple-buffered LDS + counted vmcnt (no vmcnt(0) drain in main
// loop) + setprio + XCD swizzle; prep fused to 1 kernel; Q+KV GEMMs merged.
// Launches: prep -> gemm_qkv -> attn -> gemm_out  (4 total, was 9).

typedef _Float16 f16;
typedef __attribute__((ext_vector_type(8))) _Float16 f16x8;
typedef __attribute__((ext_vector_type(4))) _Float16 f16x4;
typedef __attribute__((ext_vector_type(4))) float f32x4;

__device__ __forceinline__ void gload16(const void* g, void* l) {
  __builtin_amdgcn_global_load_lds(
      (__attribute__((address_space(1))) void*)(uintptr_t)g,
      (__attribute__((address_space(3))) void*)(uint32_t)(uintptr_t)l,
      16, 0, 0);
}

// ---------------- fused prep: cvt Xq, cvt Xkv, transpose Wq/Wkv/Wp ----------
__device__ __forceinline__ void cvt4_job(const float* __restrict__ in,
                                         f16* __restrict__ out, int i) {
  float4 v = reinterpret_cast<const float4*>(in)[i];
  f16x4 o = {(f16)v.x, (f16)v.y, (f16)v.z, (f16)v.w};
  reinterpret_cast<f16x4*>(out)[i] = o;
}
__device__ __forceinline__ void transw_job(const float* __restrict__ W,
                                           f16* __restrict__ Wt, int N, int bid,
                                           int tid) {
  int kcb = bid % 96;  // 96 = 768/8
  int n = (bid / 96) * 256 + tid;
  int k0 = kcb * 8;
  f16x8 o;
#pragma unroll
  for (int j = 0; j < 8; ++j) o[j] = (f16)W[(size_t)(k0 + j) * N + n];
  *reinterpret_cast<f16x8*>(Wt + (size_t)n * 768 + k0) = o;
}
__global__ __launch_bounds__(256) void prep_kernel(
    const float* __restrict__ Xq, const float* __restrict__ Xkv,
    const float* __restrict__ Wq, const float* __restrict__ Wkv,
    const float* __restrict__ Wp, f16* __restrict__ Xq_h,
    f16* __restrict__ Xkv_h, f16* __restrict__ WqT, f16* __restrict__ WkvT,
    f16* __restrict__ WpT) {
  const int bid = blockIdx.x, tid = threadIdx.x;
  if (bid < 3072) cvt4_job(Xq, Xq_h, bid * 256 + tid);
  else if (bid < 6144) cvt4_job(Xkv, Xkv_h, (bid - 3072) * 256 + tid);
  else if (bid < 6432) transw_job(Wq, WqT, 768, bid - 6144, tid);
  else if (bid < 7008) transw_job(Wkv, WkvT, 1536, bid - 6432, tid);
  else transw_job(Wp, WpT, 768, bid - 7008, tid);
}

// ---------------- GEMM body: C = A(4096x768) * Bt(N x 768)^T + bias ---------
// Tile 128x128, BK=32, 4 waves (2x2).  LDS [kchunk(4)][row(128)][8 f16].
template <int NDIM, int EPI>
__device__ __forceinline__ void gemm_body(int bid, f16* As, f16* Bs,
                                          const f16* __restrict__ A,
                                          const f16* __restrict__ Bt,
                                          const float* __restrict__ bias,
                                          void* __restrict__ out0,
                                          void* __restrict__ out1) {
  constexpr int KD = 768;
  const int t = threadIdx.x;
  const int lane = t & 63, wid = t >> 6;
  const int bm = bid / (NDIM / 128), bn = bid % (NDIM / 128);
  const int m0 = bm * 128, n0 = bn * 128;
  const int wm = wid >> 1, wn = wid & 1;
  const int cr = lane & 15, grp = lane >> 4;
  f32x4 acc[4][4] = {};
  for (int k0 = 0; k0 < KD; k0 += 32) {
    __syncthreads();
#pragma unroll
    for (int it = 0; it < 2; ++it) {
      int ia = it * 256 + wid * 64 + lane;
      int kc = ia >> 7, row = ia & 127;
      gload16(A + (size_t)(m0 + row) * KD + k0 + kc * 8,
              As + (it * 256 + wid * 64) * 8);
      gload16(Bt + (size_t)(n0 + row) * KD + k0 + kc * 8,
              Bs + (it * 256 + wid * 64) * 8);
    }
    __syncthreads();
    f16x8 af[4], bf[4];
#pragma unroll
    for (int mf = 0; mf < 4; ++mf)
      af[mf] = *reinterpret_cast<const f16x8*>(As + (grp * 128 + wm * 64 + mf * 16 + cr) * 8);
#pragma unroll
    for (int nf = 0; nf < 4; ++nf)
      bf[nf] = *reinterpret_cast<const f16x8*>(Bs + (grp * 128 + wn * 64 + nf * 16 + cr) * 8);
#pragma unroll
    for (int mf = 0; mf < 4; ++mf)
#pragma unroll
      for (int nf = 0; nf < 4; ++nf)
        acc[mf][nf] = __builtin_amdgcn_mfma_f32_16x16x32_f16(af[mf], bf[nf], acc[mf][nf], 0, 0, 0);
  }
#pragma unroll
  for (int mf = 0; mf < 4; ++mf) {
    int m = m0 + wm * 64 + mf * 16 + grp * 4;  // +r per reg
    int b = m >> 10, lrow = m & 1023;
#pragma unroll
    for (int nf = 0; nf < 4; ++nf) {
      int n = n0 + wn * 64 + nf * 16 + cr;
      float bv = bias[n];
      f32x4 v = acc[mf][nf];
      if constexpr (EPI == 0) {
        int h = n >> 6, d = n & 63;
        f16* dst = (f16*)out0 + (((size_t)b * 12 + h) * 1024 + lrow) * 64 + d;
#pragma unroll
        for (int r = 0; r < 4; ++r) dst[(size_t)r * 64] = (f16)((v[r] + bv) * 0.125f);
      } else if constexpr (EPI == 1) {
        if (n < 768) {
          int h = n >> 6, d = n & 63;
          f16* dst = (f16*)out0 + (((size_t)b * 12 + h) * 1024 + lrow) * 64 + d;
#pragma unroll
          for (int r = 0; r < 4; ++r) dst[(size_t)r * 64] = (f16)(v[r] + bv);
        } else {
          int n2 = n - 768;
          int h = n2 >> 6, d = n2 & 63;
          f16x4 o;
#pragma unroll
          for (int r = 0; r < 4; ++r) o[r] = (f16)(v[r] + bv);
          *reinterpret_cast<f16x4*>((f16*)out1 + (((size_t)b * 12 + h) * 64 + d) * 1024 + lrow) = o;
        }
      } else {
        float* dst = (float*)out0 + (size_t)m * 768 + n;
#pragma unroll
        for (int r = 0; r < 4; ++r) dst[(size_t)r * 768] = v[r] + bv;
      }
    }
  }
}

// merged Q + KV projection (576 blocks: 192 Q + 384 KV), XCD-swizzled
__global__ __launch_bounds__(256) void gemm_qkv_kernel(
    const f16* __restrict__ Xq_h, const f16* __restrict__ WqT,
    const float* __restrict__ bq, f16* __restrict__ Qb,
    const f16* __restrict__ Xkv_h, const f16* __restrict__ WkvT,
    const float* __restrict__ bkv, f16* __restrict__ Kb, f16* __restrict__ VTb) {
  __shared__ f16 As[4096];
  __shared__ f16 Bs[4096];
  const int swz = (blockIdx.x % 8) * 72 + blockIdx.x / 8;  // 576 = 8*72
  if (swz < 192)
    gemm_body<768, 0>(swz, As, Bs, Xq_h, WqT, bq, Qb, nullptr);
  else
    gemm_body<1536, 1>(swz - 192, As, Bs, Xkv_h, WkvT, bkv, Kb, VTb);
}

__global__ __launch_bounds__(256) void gemm_out_kernel(
    const f16* __restrict__ attO, const f16* __restrict__ WpT,
    const float* __restrict__ bp, float* __restrict__ out) {
  __shared__ f16 As[4096];
  __shared__ f16 Bs[4096];
  const int swz = (blockIdx.x % 8) * 24 + blockIdx.x / 8;  // 192 = 8*24
  gemm_body<768, 2>(swz, As, Bs, attO, WpT, bp, out, nullptr);
}

// ---------------- fused flash attention, triple-buffer + counted vmcnt ------
// Grid 768 blocks (XCD-swizzled), 4 waves (16 q-rows each), KVBLK=64, 16 tiles.
// Per tile: issue stage(t+2) [8 VMEM/lane]; s_waitcnt vmcnt(16) (tile t's group
// done, 16 ops of t+1/t+2 stay in flight ACROSS the barrier); s_barrier;
// compute(t); s_barrier (protects buf t%3 from stage(t+3) overwrite).
__global__ __launch_bounds__(256, 3) void attn_kernel(
    const f16* __restrict__ Q, const f16* __restrict__ K,
    const f16* __restrict__ VT, const float* __restrict__ pos,
    const float* __restrict__ mask, f16* __restrict__ attO) {
  __shared__ f16 Ks[3][4096];  // [dc 0..7][kv 0..63][8]
  __shared__ f16 Vs[3][4096];  // [kc8 0..7][d 0..63][8]
  const int t = threadIdx.x;
  const int lane = t & 63, wid = t >> 6;
  const int blk = (blockIdx.x % 8) * 96 + blockIdx.x / 8;  // XCD swizzle, 768=8*96
  const int bh = blk >> 4;  // b*12+h
  const int h = bh % 12, b = bh / 12;
  const int cq = lane & 15, grp = lane >> 4;
  const int q = (blk & 15) * 64 + wid * 16 + cq;
  const f16* Qp = Q + ((size_t)bh * 1024 + q) * 64 + grp * 8;
  const f16x8 qf0 = *reinterpret_cast<const f16x8*>(Qp);
  const f16x8 qf1 = *reinterpret_cast<const f16x8*>(Qp + 32);
  const f16* Kb = K + (size_t)bh * 1024 * 64;
  const f16* Vb = VT + (size_t)bh * 64 * 1024;
  const float* pb = pos + ((size_t)h * 1024 + q) * 1024;

  float m_run = -1e30f, l_run = 0.f;
  f32x4 acc[4] = {};  // O^T: acc[df][r] -> d = df*16 + grp*4 + r, col q
  f32x4 ps[3][4];

  auto stageKV = [&](f16* Ksb, f16* Vsb, int kv0) {
#pragma unroll
    for (int it = 0; it < 2; ++it) {
      int ci = it * 256 + t;
      int hi = ci >> 6, lo = ci & 63;
      gload16(Kb + (size_t)(kv0 + lo) * 64 + hi * 8, Ksb + ci * 8);
      gload16(Vb + (size_t)lo * 1024 + kv0 + hi * 8, Vsb + ci * 8);
    }
  };
  auto loadpos = [&](f32x4* psX, int kv0) {
#pragma unroll
    for (int f = 0; f < 4; ++f)
      psX[f] = *reinterpret_cast<const f32x4*>(pb + kv0 + f * 16 + grp * 4);
  };
  auto compute = [&](const f16* Ksb, const f16* Vsb, const f32x4* psX) {
    f32x4 st[4];
    __builtin_amdgcn_s_setprio(1);
#pragma unroll
    for (int f = 0; f < 4; ++f) {
      f16x8 kf0 = *reinterpret_cast<const f16x8*>(Ksb + (grp * 64 + f * 16 + cq) * 8);
      f16x8 kf1 = *reinterpret_cast<const f16x8*>(Ksb + ((4 + grp) * 64 + f * 16 + cq) * 8);
      f32x4 z = {0.f, 0.f, 0.f, 0.f};
      z = __builtin_amdgcn_mfma_f32_16x16x32_f16(kf0, qf0, z, 0, 0, 0);
      z = __builtin_amdgcn_mfma_f32_16x16x32_f16(kf1, qf1, z, 0, 0, 0);
      st[f] = z + psX[f];
    }
    __builtin_amdgcn_s_setprio(0);
    float tm = -1e30f;
#pragma unroll
    for (int f = 0; f < 4; ++f)
#pragma unroll
      for (int r = 0; r < 4; ++r) tm = fmaxf(tm, st[f][r]);
    tm = fmaxf(tm, __shfl_xor(tm, 16));
    tm = fmaxf(tm, __shfl_xor(tm, 32));
    const float m_new = fmaxf(m_run, tm);
    const float corr = __expf(m_run - m_new);
    float ls = 0.f;
    f16x4 pf[4];
#pragma unroll
    for (int f = 0; f < 4; ++f)
#pragma unroll
      for (int r = 0; r < 4; ++r) {
        float p = __expf(st[f][r] - m_new);
        ls += p;
        pf[f][r] = (f16)p;
      }
    ls += __shfl_xor(ls, 16);
    ls += __shfl_xor(ls, 32);
    l_run = l_run * corr + ls;
    m_run = m_new;
#pragma unroll
    for (int df = 0; df < 4; ++df) acc[df] *= corr;
    __builtin_amdgcn_s_setprio(1);
#pragma unroll
    for (int f = 0; f < 4; ++f)
#pragma unroll
      for (int df = 0; df < 4; ++df) {
        f16x4 vf = *reinterpret_cast<const f16x4*>(
            Vsb + ((f * 2 + (grp >> 1)) * 64 + df * 16 + cq) * 8 + (grp & 1) * 4);
        acc[df] = __builtin_amdgcn_mfma_f32_16x16x16f16(vf, pf[f], acc[df], 0, 0, 0);
      }
    __builtin_amdgcn_s_setprio(0);
  };

  // prologue: stage tiles 0 and 1 (16 VMEM ops/lane in flight)
  stageKV(Ks[0], Vs[0], 0);
  loadpos(ps[0], 0);
  asm volatile("" ::: "memory");
  stageKV(Ks[1], Vs[1], 64);
  loadpos(ps[1], 64);
  asm volatile("" ::: "memory");

#pragma unroll
  for (int tile = 0; tile < 16; ++tile) {
    const int cur = tile % 3;
    const int nx = (tile + 2) % 3;
    if (tile + 2 < 16) {
      stageKV(Ks[nx], Vs[nx], (tile + 2) * 64);
      loadpos(ps[nx], (tile + 2) * 64);
      asm volatile("" ::: "memory");
    }
    if (tile <= 13)
      asm volatile("s_waitcnt vmcnt(16)" ::: "memory");
    else if (tile == 14)
      asm volatile("s_waitcnt vmcnt(8)" ::: "memory");
    else
      asm volatile("s_waitcnt vmcnt(0)" ::: "memory");
    __builtin_amdgcn_s_barrier();
    compute(Ks[cur], Vs[cur], ps[cur]);
    if (tile < 15) __builtin_amdgcn_s_barrier();
  }

  const float sc = mask[b * 1024 + q] / l_run;
  f16* ob = attO + ((size_t)b * 1024 + q) * 768 + h * 64;
#pragma unroll
  for (int df = 0; df < 4; ++df) {
    f16x4 o;
#pragma unroll
    for (int r = 0; r < 4; ++r) o[r] = (f16)(acc[df][r] * sc);
    *reinterpret_cast<f16x4*>(ob + df * 16 + grp * 4) = o;
  }
}

extern "C" void kernel_launch(void* const* d_in, const int* in_sizes, int n_in,
                              void* d_out, int out_size, void* d_ws, size_t ws_size,
                              hipStream_t stream) {
  const float* Xq   = (const float*)d_in[0];
  const float* Xkv  = (const float*)d_in[1];
  const float* mask = (const float*)d_in[2];
  const float* Wq   = (const float*)d_in[3];
  const float* bq   = (const float*)d_in[4];
  const float* Wkv  = (const float*)d_in[5];
  const float* bkv  = (const float*)d_in[6];
  const float* Wp   = (const float*)d_in[7];
  const float* bp   = (const float*)d_in[8];
  const float* pos  = (const float*)d_in[9];
  float* out = (float*)d_out;
  char* ws = (char*)d_ws;
  if (ws_size < 42467328) return;  // need ~42.5 MB scratch

  f16* Xq_h  = (f16*)(ws + 0);         // 4096*768
  f16* Xkv_h = (f16*)(ws + 6291456);   // 4096*768
  f16* WqT   = (f16*)(ws + 12582912);  // 768*768
  f16* WkvT  = (f16*)(ws + 13762560);  // 1536*768
  f16* WpT   = (f16*)(ws + 16121856);  // 768*768
  f16* Qb    = (f16*)(ws + 17301504);  // (B,NH,LQ,HD)
  f16* Kb    = (f16*)(ws + 23592960);  // (B,NH,LKV,HD)
  f16* VTb   = (f16*)(ws + 29884416);  // (B,NH,HD,LKV)
  f16* attO  = (f16*)(ws + 36175872);  // (B,LQ,EMBED)

  prep_kernel<<<7296, 256, 0, stream>>>(Xq, Xkv, Wq, Wkv, Wp, Xq_h, Xkv_h, WqT,
                                        WkvT, WpT);
  gemm_qkv_kernel<<<576, 256, 0, stream>>>(Xq_h, WqT, bq, Qb, Xkv_h, WkvT, bkv,
                                           Kb, VTb);
  attn_kernel<<<768, 256, 0, stream>>>(Qb, Kb, VTb, pos, mask, attO);
  gemm_out_kernel<<<192, 256, 0, stream>>>(attO, WpT, bp, out);
}

// Round 5
// 137.721 us; speedup vs baseline: 1.2852x; 1.2852x over previous
//
#include <hip/hip_runtime.h>
#include <hip/hip_fp16.h>
#include <stdint.h>

// MaskCrossAttention: B=4, LQ=LKV=1024, C=EMBED=768, NH=12, HD=64, SCALE=0.125
// Round 4: attn = r2 skeleton + triple-buffer K/V LDS + counted vmcnt, with
// ZERO indexed local arrays (r3's ps[3][4] spilled -> 190MB scratch traffic).
// Six named __shared__ buffers + 16 macro-instantiated tile steps.
// Launches: prep -> gemm_qkv -> attn -> gemm_out.

typedef _Float16 f16;
typedef __attribute__((ext_vector_type(8))) _Float16 f16x8;
typedef __attribute__((ext_vector_type(4))) _Float16 f16x4;
typedef __attribute__((ext_vector_type(4))) float f32x4;

__device__ __forceinline__ void gload16(const void* g, void* l) {
  __builtin_amdgcn_global_load_lds(
      (__attribute__((address_space(1))) void*)(uintptr_t)g,
      (__attribute__((address_space(3))) void*)(uint32_t)(uintptr_t)l,
      16, 0, 0);
}

// ---------------- fused prep: cvt Xq, cvt Xkv, transpose Wq/Wkv/Wp ----------
__device__ __forceinline__ void cvt4_job(const float* __restrict__ in,
                                         f16* __restrict__ out, int i) {
  float4 v = reinterpret_cast<const float4*>(in)[i];
  f16x4 o = {(f16)v.x, (f16)v.y, (f16)v.z, (f16)v.w};
  reinterpret_cast<f16x4*>(out)[i] = o;
}
__device__ __forceinline__ void transw_job(const float* __restrict__ W,
                                           f16* __restrict__ Wt, int N, int bid,
                                           int tid) {
  int kcb = bid % 96;  // 96 = 768/8
  int n = (bid / 96) * 256 + tid;
  int k0 = kcb * 8;
  f16x8 o;
#pragma unroll
  for (int j = 0; j < 8; ++j) o[j] = (f16)W[(size_t)(k0 + j) * N + n];
  *reinterpret_cast<f16x8*>(Wt + (size_t)n * 768 + k0) = o;
}
__global__ __launch_bounds__(256) void prep_kernel(
    const float* __restrict__ Xq, const float* __restrict__ Xkv,
    const float* __restrict__ Wq, const float* __restrict__ Wkv,
    const float* __restrict__ Wp, f16* __restrict__ Xq_h,
    f16* __restrict__ Xkv_h, f16* __restrict__ WqT, f16* __restrict__ WkvT,
    f16* __restrict__ WpT) {
  const int bid = blockIdx.x, tid = threadIdx.x;
  if (bid < 3072) cvt4_job(Xq, Xq_h, bid * 256 + tid);
  else if (bid < 6144) cvt4_job(Xkv, Xkv_h, (bid - 3072) * 256 + tid);
  else if (bid < 6432) transw_job(Wq, WqT, 768, bid - 6144, tid);
  else if (bid < 7008) transw_job(Wkv, WkvT, 1536, bid - 6432, tid);
  else transw_job(Wp, WpT, 768, bid - 7008, tid);
}

// ---------------- GEMM body: C = A(4096x768) * Bt(N x 768)^T + bias ---------
template <int NDIM, int EPI>
__device__ __forceinline__ void gemm_body(int bid, f16* As, f16* Bs,
                                          const f16* __restrict__ A,
                                          const f16* __restrict__ Bt,
                                          const float* __restrict__ bias,
                                          void* __restrict__ out0,
                                          void* __restrict__ out1) {
  constexpr int KD = 768;
  const int t = threadIdx.x;
  const int lane = t & 63, wid = t >> 6;
  const int bm = bid / (NDIM / 128), bn = bid % (NDIM / 128);
  const int m0 = bm * 128, n0 = bn * 128;
  const int wm = wid >> 1, wn = wid & 1;
  const int cr = lane & 15, grp = lane >> 4;
  f32x4 acc[4][4] = {};
  for (int k0 = 0; k0 < KD; k0 += 32) {
    __syncthreads();
#pragma unroll
    for (int it = 0; it < 2; ++it) {
      int ia = it * 256 + wid * 64 + lane;
      int kc = ia >> 7, row = ia & 127;
      gload16(A + (size_t)(m0 + row) * KD + k0 + kc * 8,
              As + (it * 256 + wid * 64) * 8);
      gload16(Bt + (size_t)(n0 + row) * KD + k0 + kc * 8,
              Bs + (it * 256 + wid * 64) * 8);
    }
    __syncthreads();
    f16x8 af[4], bf[4];
#pragma unroll
    for (int mf = 0; mf < 4; ++mf)
      af[mf] = *reinterpret_cast<const f16x8*>(As + (grp * 128 + wm * 64 + mf * 16 + cr) * 8);
#pragma unroll
    for (int nf = 0; nf < 4; ++nf)
      bf[nf] = *reinterpret_cast<const f16x8*>(Bs + (grp * 128 + wn * 64 + nf * 16 + cr) * 8);
#pragma unroll
    for (int mf = 0; mf < 4; ++mf)
#pragma unroll
      for (int nf = 0; nf < 4; ++nf)
        acc[mf][nf] = __builtin_amdgcn_mfma_f32_16x16x32_f16(af[mf], bf[nf], acc[mf][nf], 0, 0, 0);
  }
#pragma unroll
  for (int mf = 0; mf < 4; ++mf) {
    int m = m0 + wm * 64 + mf * 16 + grp * 4;  // +r per reg
    int b = m >> 10, lrow = m & 1023;
#pragma unroll
    for (int nf = 0; nf < 4; ++nf) {
      int n = n0 + wn * 64 + nf * 16 + cr;
      float bv = bias[n];
      f32x4 v = acc[mf][nf];
      if constexpr (EPI == 0) {
        int h = n >> 6, d = n & 63;
        f16* dst = (f16*)out0 + (((size_t)b * 12 + h) * 1024 + lrow) * 64 + d;
#pragma unroll
        for (int r = 0; r < 4; ++r) dst[(size_t)r * 64] = (f16)((v[r] + bv) * 0.125f);
      } else if constexpr (EPI == 1) {
        if (n < 768) {
          int h = n >> 6, d = n & 63;
          f16* dst = (f16*)out0 + (((size_t)b * 12 + h) * 1024 + lrow) * 64 + d;
#pragma unroll
          for (int r = 0; r < 4; ++r) dst[(size_t)r * 64] = (f16)(v[r] + bv);
        } else {
          int n2 = n - 768;
          int h = n2 >> 6, d = n2 & 63;
          f16x4 o;
#pragma unroll
          for (int r = 0; r < 4; ++r) o[r] = (f16)(v[r] + bv);
          *reinterpret_cast<f16x4*>((f16*)out1 + (((size_t)b * 12 + h) * 64 + d) * 1024 + lrow) = o;
        }
      } else {
        float* dst = (float*)out0 + (size_t)m * 768 + n;
#pragma unroll
        for (int r = 0; r < 4; ++r) dst[(size_t)r * 768] = v[r] + bv;
      }
    }
  }
}

__global__ __launch_bounds__(256) void gemm_qkv_kernel(
    const f16* __restrict__ Xq_h, const f16* __restrict__ WqT,
    const float* __restrict__ bq, f16* __restrict__ Qb,
    const f16* __restrict__ Xkv_h, const f16* __restrict__ WkvT,
    const float* __restrict__ bkv, f16* __restrict__ Kb, f16* __restrict__ VTb) {
  __shared__ f16 As[4096];
  __shared__ f16 Bs[4096];
  const int swz = (blockIdx.x % 8) * 72 + blockIdx.x / 8;  // 576 = 8*72
  if (swz < 192)
    gemm_body<768, 0>(swz, As, Bs, Xq_h, WqT, bq, Qb, nullptr);
  else
    gemm_body<1536, 1>(swz - 192, As, Bs, Xkv_h, WkvT, bkv, Kb, VTb);
}

__global__ __launch_bounds__(256) void gemm_out_kernel(
    const f16* __restrict__ attO, const f16* __restrict__ WpT,
    const float* __restrict__ bp, float* __restrict__ out) {
  __shared__ f16 As[4096];
  __shared__ f16 Bs[4096];
  const int swz = (blockIdx.x % 8) * 24 + blockIdx.x / 8;  // 192 = 8*24
  gemm_body<768, 2>(swz, As, Bs, attO, WpT, bp, out, nullptr);
}

// ---------------- fused flash attention: 3-buffer LDS, counted vmcnt --------
// 768 blocks (XCD swizzle), 4 waves x 16 q-rows, KVBLK=64, 16 tiles.
// Tile t: issue {stage(t+2), pos(t+1)} as one pinned 8-op group; vmcnt(16)
// drains exactly stage(t) (two younger groups stay in flight across barrier);
// s_barrier; compute(t); s_barrier. pos frags in named psA/psB only.
__global__ __launch_bounds__(256, 3) void attn_kernel(
    const f16* __restrict__ Q, const f16* __restrict__ K,
    const f16* __restrict__ VT, const float* __restrict__ pos,
    const float* __restrict__ mask, f16* __restrict__ attO) {
  __shared__ f16 Ks0[4096], Ks1[4096], Ks2[4096];  // [dc 0..7][kv 0..63][8]
  __shared__ f16 Vs0[4096], Vs1[4096], Vs2[4096];  // [kc8 0..7][d 0..63][8]
  const int t = threadIdx.x;
  const int lane = t & 63, wid = t >> 6;
  const int blk = (blockIdx.x % 8) * 96 + blockIdx.x / 8;  // 768 = 8*96
  const int bh = blk >> 4;  // b*12+h
  const int h = bh % 12, b = bh / 12;
  const int cq = lane & 15, grp = lane >> 4;
  const int q = (blk & 15) * 64 + wid * 16 + cq;
  const f16* Qp = Q + ((size_t)bh * 1024 + q) * 64 + grp * 8;
  const f16x8 qf0 = *reinterpret_cast<const f16x8*>(Qp);
  const f16x8 qf1 = *reinterpret_cast<const f16x8*>(Qp + 32);
  const f16* Kb = K + (size_t)bh * 1024 * 64;
  const f16* Vb = VT + (size_t)bh * 64 * 1024;
  const float* pb = pos + ((size_t)h * 1024 + q) * 1024;

  float m_run = -1e30f, l_run = 0.f;
  f32x4 acc[4] = {};  // O^T: acc[df][r] -> d = df*16 + grp*4 + r, col q
  f32x4 psA[4], psB[4];

  auto stageKV = [&](f16* Ksb, f16* Vsb, int kv0) {
#pragma unroll
    for (int it = 0; it < 2; ++it) {
      int ci = it * 256 + t;
      int hi = ci >> 6, lo = ci & 63;
      gload16(Kb + (size_t)(kv0 + lo) * 64 + hi * 8, Ksb + ci * 8);
      gload16(Vb + (size_t)lo * 1024 + kv0 + hi * 8, Vsb + ci * 8);
    }
  };
  auto loadpos = [&](f32x4* psX, int kv0) {
#pragma unroll
    for (int f = 0; f < 4; ++f)
      psX[f] = *reinterpret_cast<const f32x4*>(pb + kv0 + f * 16 + grp * 4);
  };
  auto compute = [&](const f16* Ksb, const f16* Vsb, const f32x4* psX) {
    f32x4 st[4];
    __builtin_amdgcn_s_setprio(1);
#pragma unroll
    for (int f = 0; f < 4; ++f) {
      f16x8 kf0 = *reinterpret_cast<const f16x8*>(Ksb + (grp * 64 + f * 16 + cq) * 8);
      f16x8 kf1 = *reinterpret_cast<const f16x8*>(Ksb + ((4 + grp) * 64 + f * 16 + cq) * 8);
      f32x4 z = {0.f, 0.f, 0.f, 0.f};
      z = __builtin_amdgcn_mfma_f32_16x16x32_f16(kf0, qf0, z, 0, 0, 0);
      z = __builtin_amdgcn_mfma_f32_16x16x32_f16(kf1, qf1, z, 0, 0, 0);
      st[f] = z + psX[f];
    }
    __builtin_amdgcn_s_setprio(0);
    float tm = -1e30f;
#pragma unroll
    for (int f = 0; f < 4; ++f)
#pragma unroll
      for (int r = 0; r < 4; ++r) tm = fmaxf(tm, st[f][r]);
    tm = fmaxf(tm, __shfl_xor(tm, 16));
    tm = fmaxf(tm, __shfl_xor(tm, 32));
    const float m_new = fmaxf(m_run, tm);
    const float corr = __expf(m_run - m_new);
    float ls = 0.f;
    f16x4 pf[4];
#pragma unroll
    for (int f = 0; f < 4; ++f)
#pragma unroll
      for (int r = 0; r < 4; ++r) {
        float p = __expf(st[f][r] - m_new);
        ls += p;
        pf[f][r] = (f16)p;
      }
    ls += __shfl_xor(ls, 16);
    ls += __shfl_xor(ls, 32);
    l_run = l_run * corr + ls;
    m_run = m_new;
#pragma unroll
    for (int df = 0; df < 4; ++df) acc[df] *= corr;
    __builtin_amdgcn_s_setprio(1);
#pragma unroll
    for (int f = 0; f < 4; ++f)
#pragma unroll
      for (int df = 0; df < 4; ++df) {
        f16x4 vf = *reinterpret_cast<const f16x4*>(
            Vsb + ((f * 2 + (grp >> 1)) * 64 + df * 16 + cq) * 8 + (grp & 1) * 4);
        acc[df] = __builtin_amdgcn_mfma_f32_16x16x16f16(vf, pf[f], acc[df], 0, 0, 0);
      }
    __builtin_amdgcn_s_setprio(0);
  };

  // prologue: G-2 = {stage(0), pos(0)}, G-1 = {stage(1)}
  stageKV(Ks0, Vs0, 0);
  loadpos(psA, 0);
  asm volatile("" ::: "memory");
  stageKV(Ks1, Vs1, 64);
  asm volatile("" ::: "memory");

  // Tile t: stage->(t+2)%3 buffer, pos->ps[(t+1)&1]; compute (t%3, ps[t&1]).
  // vmcnt: t=0 ->12 (G-1 only 4 ops), 1..13 ->16, 14 ->12, 15 ->4.
#define TILE_STEP(T, KC, VC, KN, VN, PSC, PSN, VM)                        \
  {                                                                       \
    if ((T) + 2 < 16) stageKV(KN, VN, ((T) + 2) * 64);                    \
    if ((T) + 1 < 16) loadpos(PSN, ((T) + 1) * 64);                       \
    asm volatile("" ::: "memory");                                        \
    asm volatile("s_waitcnt vmcnt(" #VM ")" ::: "memory");                \
    __builtin_amdgcn_s_barrier();                                         \
    compute(KC, VC, PSC);                                                 \
    if ((T) < 15) __builtin_amdgcn_s_barrier();                           \
  }

  TILE_STEP(0,  Ks0, Vs0, Ks2, Vs2, psA, psB, 12)
  TILE_STEP(1,  Ks1, Vs1, Ks0, Vs0, psB, psA, 16)
  TILE_STEP(2,  Ks2, Vs2, Ks1, Vs1, psA, psB, 16)
  TILE_STEP(3,  Ks0, Vs0, Ks2, Vs2, psB, psA, 16)
  TILE_STEP(4,  Ks1, Vs1, Ks0, Vs0, psA, psB, 16)
  TILE_STEP(5,  Ks2, Vs2, Ks1, Vs1, psB, psA, 16)
  TILE_STEP(6,  Ks0, Vs0, Ks2, Vs2, psA, psB, 16)
  TILE_STEP(7,  Ks1, Vs1, Ks0, Vs0, psB, psA, 16)
  TILE_STEP(8,  Ks2, Vs2, Ks1, Vs1, psA, psB, 16)
  TILE_STEP(9,  Ks0, Vs0, Ks2, Vs2, psB, psA, 16)
  TILE_STEP(10, Ks1, Vs1, Ks0, Vs0, psA, psB, 16)
  TILE_STEP(11, Ks2, Vs2, Ks1, Vs1, psB, psA, 16)
  TILE_STEP(12, Ks0, Vs0, Ks2, Vs2, psA, psB, 16)
  TILE_STEP(13, Ks1, Vs1, Ks0, Vs0, psB, psA, 16)
  TILE_STEP(14, Ks2, Vs2, Ks1, Vs1, psA, psB, 12)
  TILE_STEP(15, Ks0, Vs0, Ks2, Vs2, psB, psA, 4)
#undef TILE_STEP

  const float sc = mask[b * 1024 + q] / l_run;
  f16* ob = attO + ((size_t)b * 1024 + q) * 768 + h * 64;
#pragma unroll
  for (int df = 0; df < 4; ++df) {
    f16x4 o;
#pragma unroll
    for (int r = 0; r < 4; ++r) o[r] = (f16)(acc[df][r] * sc);
    *reinterpret_cast<f16x4*>(ob + df * 16 + grp * 4) = o;
  }
}

extern "C" void kernel_launch(void* const* d_in, const int* in_sizes, int n_in,
                              void* d_out, int out_size, void* d_ws, size_t ws_size,
                              hipStream_t stream) {
  const float* Xq   = (const float*)d_in[0];
  const float* Xkv  = (const float*)d_in[1];
  const float* mask = (const float*)d_in[2];
  const float* Wq   = (const float*)d_in[3];
  const float* bq   = (const float*)d_in[4];
  const float* Wkv  = (const float*)d_in[5];
  const float* bkv  = (const float*)d_in[6];
  const float* Wp   = (const float*)d_in[7];
  const float* bp   = (const float*)d_in[8];
  const float* pos  = (const float*)d_in[9];
  float* out = (float*)d_out;
  char* ws = (char*)d_ws;
  if (ws_size < 42467328) return;  // need ~42.5 MB scratch

  f16* Xq_h  = (f16*)(ws + 0);         // 4096*768
  f16* Xkv_h = (f16*)(ws + 6291456);   // 4096*768
  f16* WqT   = (f16*)(ws + 12582912);  // 768*768
  f16* WkvT  = (f16*)(ws + 13762560);  // 1536*768
  f16* WpT   = (f16*)(ws + 16121856);  // 768*768
  f16* Qb    = (f16*)(ws + 17301504);  // (B,NH,LQ,HD)
  f16* Kb    = (f16*)(ws + 23592960);  // (B,NH,LKV,HD)
  f16* VTb   = (f16*)(ws + 29884416);  // (B,NH,HD,LKV)
  f16* attO  = (f16*)(ws + 36175872);  // (B,LQ,EMBED)

  prep_kernel<<<7296, 256, 0, stream>>>(Xq, Xkv, Wq, Wkv, Wp, Xq_h, Xkv_h, WqT,
                                        WkvT, WpT);
  gemm_qkv_kernel<<<576, 256, 0, stream>>>(Xq_h, WqT, bq, Qb, Xkv_h, WkvT, bkv,
                                           Kb, VTb);
  attn_kernel<<<768, 256, 0, stream>>>(Qb, Kb, VTb, pos, mask, attO);
  gemm_out_kernel<<<192, 256, 0, stream>>>(attO, WpT, bp, out);
}

// Round 6
// 137.407 us; speedup vs baseline: 1.2881x; 1.0023x over previous
//
#include <hip/hip_runtime.h>
#include <hip/hip_fp16.h>
#include <stdint.h>

// MaskCrossAttention: B=4, LQ=LKV=1024, C=EMBED=768, NH=12, HD=64, SCALE=0.125
// Round 5: attn keeps r4's 3-buffer/counted-vmcnt schedule; adds
//  (1) pos-sharing block remap: 4 batches with same (h,qtile) -> same XCD so
//      attn_pos is L2-served (was L3/HBM via scattered XCDs),
//  (2) T13 defer-rescale (THR=8): skip corr/rescale when max doesn't grow.
// Launches: prep -> gemm_qkv -> attn -> gemm_out.

typedef _Float16 f16;
typedef __attribute__((ext_vector_type(8))) _Float16 f16x8;
typedef __attribute__((ext_vector_type(4))) _Float16 f16x4;
typedef __attribute__((ext_vector_type(4))) float f32x4;

__device__ __forceinline__ void gload16(const void* g, void* l) {
  __builtin_amdgcn_global_load_lds(
      (__attribute__((address_space(1))) void*)(uintptr_t)g,
      (__attribute__((address_space(3))) void*)(uint32_t)(uintptr_t)l,
      16, 0, 0);
}

// ---------------- fused prep: cvt Xq, cvt Xkv, transpose Wq/Wkv/Wp ----------
__device__ __forceinline__ void cvt4_job(const float* __restrict__ in,
                                         f16* __restrict__ out, int i) {
  float4 v = reinterpret_cast<const float4*>(in)[i];
  f16x4 o = {(f16)v.x, (f16)v.y, (f16)v.z, (f16)v.w};
  reinterpret_cast<f16x4*>(out)[i] = o;
}
__device__ __forceinline__ void transw_job(const float* __restrict__ W,
                                           f16* __restrict__ Wt, int N, int bid,
                                           int tid) {
  int kcb = bid % 96;  // 96 = 768/8
  int n = (bid / 96) * 256 + tid;
  int k0 = kcb * 8;
  f16x8 o;
#pragma unroll
  for (int j = 0; j < 8; ++j) o[j] = (f16)W[(size_t)(k0 + j) * N + n];
  *reinterpret_cast<f16x8*>(Wt + (size_t)n * 768 + k0) = o;
}
__global__ __launch_bounds__(256) void prep_kernel(
    const float* __restrict__ Xq, const float* __restrict__ Xkv,
    const float* __restrict__ Wq, const float* __restrict__ Wkv,
    const float* __restrict__ Wp, f16* __restrict__ Xq_h,
    f16* __restrict__ Xkv_h, f16* __restrict__ WqT, f16* __restrict__ WkvT,
    f16* __restrict__ WpT) {
  const int bid = blockIdx.x, tid = threadIdx.x;
  if (bid < 3072) cvt4_job(Xq, Xq_h, bid * 256 + tid);
  else if (bid < 6144) cvt4_job(Xkv, Xkv_h, (bid - 3072) * 256 + tid);
  else if (bid < 6432) transw_job(Wq, WqT, 768, bid - 6144, tid);
  else if (bid < 7008) transw_job(Wkv, WkvT, 1536, bid - 6432, tid);
  else transw_job(Wp, WpT, 768, bid - 7008, tid);
}

// ---------------- GEMM body: C = A(4096x768) * Bt(N x 768)^T + bias ---------
template <int NDIM, int EPI>
__device__ __forceinline__ void gemm_body(int bid, f16* As, f16* Bs,
                                          const f16* __restrict__ A,
                                          const f16* __restrict__ Bt,
                                          const float* __restrict__ bias,
                                          void* __restrict__ out0,
                                          void* __restrict__ out1) {
  constexpr int KD = 768;
  const int t = threadIdx.x;
  const int lane = t & 63, wid = t >> 6;
  const int bm = bid / (NDIM / 128), bn = bid % (NDIM / 128);
  const int m0 = bm * 128, n0 = bn * 128;
  const int wm = wid >> 1, wn = wid & 1;
  const int cr = lane & 15, grp = lane >> 4;
  f32x4 acc[4][4] = {};
  for (int k0 = 0; k0 < KD; k0 += 32) {
    __syncthreads();
#pragma unroll
    for (int it = 0; it < 2; ++it) {
      int ia = it * 256 + wid * 64 + lane;
      int kc = ia >> 7, row = ia & 127;
      gload16(A + (size_t)(m0 + row) * KD + k0 + kc * 8,
              As + (it * 256 + wid * 64) * 8);
      gload16(Bt + (size_t)(n0 + row) * KD + k0 + kc * 8,
              Bs + (it * 256 + wid * 64) * 8);
    }
    __syncthreads();
    f16x8 af[4], bf[4];
#pragma unroll
    for (int mf = 0; mf < 4; ++mf)
      af[mf] = *reinterpret_cast<const f16x8*>(As + (grp * 128 + wm * 64 + mf * 16 + cr) * 8);
#pragma unroll
    for (int nf = 0; nf < 4; ++nf)
      bf[nf] = *reinterpret_cast<const f16x8*>(Bs + (grp * 128 + wn * 64 + nf * 16 + cr) * 8);
#pragma unroll
    for (int mf = 0; mf < 4; ++mf)
#pragma unroll
      for (int nf = 0; nf < 4; ++nf)
        acc[mf][nf] = __builtin_amdgcn_mfma_f32_16x16x32_f16(af[mf], bf[nf], acc[mf][nf], 0, 0, 0);
  }
#pragma unroll
  for (int mf = 0; mf < 4; ++mf) {
    int m = m0 + wm * 64 + mf * 16 + grp * 4;  // +r per reg
    int b = m >> 10, lrow = m & 1023;
#pragma unroll
    for (int nf = 0; nf < 4; ++nf) {
      int n = n0 + wn * 64 + nf * 16 + cr;
      float bv = bias[n];
      f32x4 v = acc[mf][nf];
      if constexpr (EPI == 0) {
        int h = n >> 6, d = n & 63;
        f16* dst = (f16*)out0 + (((size_t)b * 12 + h) * 1024 + lrow) * 64 + d;
#pragma unroll
        for (int r = 0; r < 4; ++r) dst[(size_t)r * 64] = (f16)((v[r] + bv) * 0.125f);
      } else if constexpr (EPI == 1) {
        if (n < 768) {
          int h = n >> 6, d = n & 63;
          f16* dst = (f16*)out0 + (((size_t)b * 12 + h) * 1024 + lrow) * 64 + d;
#pragma unroll
          for (int r = 0; r < 4; ++r) dst[(size_t)r * 64] = (f16)(v[r] + bv);
        } else {
          int n2 = n - 768;
          int h = n2 >> 6, d = n2 & 63;
          f16x4 o;
#pragma unroll
          for (int r = 0; r < 4; ++r) o[r] = (f16)(v[r] + bv);
          *reinterpret_cast<f16x4*>((f16*)out1 + (((size_t)b * 12 + h) * 64 + d) * 1024 + lrow) = o;
        }
      } else {
        float* dst = (float*)out0 + (size_t)m * 768 + n;
#pragma unroll
        for (int r = 0; r < 4; ++r) dst[(size_t)r * 768] = v[r] + bv;
      }
    }
  }
}

__global__ __launch_bounds__(256) void gemm_qkv_kernel(
    const f16* __restrict__ Xq_h, const f16* __restrict__ WqT,
    const float* __restrict__ bq, f16* __restrict__ Qb,
    const f16* __restrict__ Xkv_h, const f16* __restrict__ WkvT,
    const float* __restrict__ bkv, f16* __restrict__ Kb, f16* __restrict__ VTb) {
  __shared__ f16 As[4096];
  __shared__ f16 Bs[4096];
  const int swz = (blockIdx.x % 8) * 72 + blockIdx.x / 8;  // 576 = 8*72
  if (swz < 192)
    gemm_body<768, 0>(swz, As, Bs, Xq_h, WqT, bq, Qb, nullptr);
  else
    gemm_body<1536, 1>(swz - 192, As, Bs, Xkv_h, WkvT, bkv, Kb, VTb);
}

__global__ __launch_bounds__(256) void gemm_out_kernel(
    const f16* __restrict__ attO, const f16* __restrict__ WpT,
    const float* __restrict__ bp, float* __restrict__ out) {
  __shared__ f16 As[4096];
  __shared__ f16 Bs[4096];
  const int swz = (blockIdx.x % 8) * 24 + blockIdx.x / 8;  // 192 = 8*24
  gemm_body<768, 2>(swz, As, Bs, attO, WpT, bp, out, nullptr);
}

// ---------------- fused flash attention: 3-buffer LDS, counted vmcnt --------
// 768 blocks, 4 waves x 16 q-rows, KVBLK=64, 16 tiles.
// Block remap: (xcd = idx&7, j = idx>>3) -> group gidx = xcd*24 + j/4 encodes
// (h,qtile); b = j&3.  The 4 b's of one (h,qtile) are consecutive on ONE XCD
// so their shared attn_pos rows are L2-resident (read once, 3 hits).
__global__ __launch_bounds__(256, 3) void attn_kernel(
    const f16* __restrict__ Q, const f16* __restrict__ K,
    const f16* __restrict__ VT, const float* __restrict__ pos,
    const float* __restrict__ mask, f16* __restrict__ attO) {
  __shared__ f16 Ks0[4096], Ks1[4096], Ks2[4096];  // [dc 0..7][kv 0..63][8]
  __shared__ f16 Vs0[4096], Vs1[4096], Vs2[4096];  // [kc8 0..7][d 0..63][8]
  const int t = threadIdx.x;
  const int lane = t & 63, wid = t >> 6;
  const int xcd = blockIdx.x & 7;
  const int j = blockIdx.x >> 3;            // 0..95
  const int gidx = xcd * 24 + (j >> 2);     // 0..191 = h*16 + qtile
  const int b = j & 3;
  const int h = gidx >> 4;
  const int qt = gidx & 15;
  const int bh = b * 12 + h;
  const int cq = lane & 15, grp = lane >> 4;
  const int q = qt * 64 + wid * 16 + cq;
  const f16* Qp = Q + ((size_t)bh * 1024 + q) * 64 + grp * 8;
  const f16x8 qf0 = *reinterpret_cast<const f16x8*>(Qp);
  const f16x8 qf1 = *reinterpret_cast<const f16x8*>(Qp + 32);
  const f16* Kb = K + (size_t)bh * 1024 * 64;
  const f16* Vb = VT + (size_t)bh * 64 * 1024;
  const float* pb = pos + ((size_t)h * 1024 + q) * 1024;

  float m_run = -1e30f, l_run = 0.f;
  f32x4 acc[4] = {};  // O^T: acc[df][r] -> d = df*16 + grp*4 + r, col q
  f32x4 psA[4], psB[4];

  auto stageKV = [&](f16* Ksb, f16* Vsb, int kv0) {
#pragma unroll
    for (int it = 0; it < 2; ++it) {
      int ci = it * 256 + t;
      int hi = ci >> 6, lo = ci & 63;
      gload16(Kb + (size_t)(kv0 + lo) * 64 + hi * 8, Ksb + ci * 8);
      gload16(Vb + (size_t)lo * 1024 + kv0 + hi * 8, Vsb + ci * 8);
    }
  };
  auto loadpos = [&](f32x4* psX, int kv0) {
#pragma unroll
    for (int f = 0; f < 4; ++f)
      psX[f] = *reinterpret_cast<const f32x4*>(pb + kv0 + f * 16 + grp * 4);
  };
  auto compute = [&](const f16* Ksb, const f16* Vsb, const f32x4* psX) {
    f32x4 st[4];
    __builtin_amdgcn_s_setprio(1);
#pragma unroll
    for (int f = 0; f < 4; ++f) {
      f16x8 kf0 = *reinterpret_cast<const f16x8*>(Ksb + (grp * 64 + f * 16 + cq) * 8);
      f16x8 kf1 = *reinterpret_cast<const f16x8*>(Ksb + ((4 + grp) * 64 + f * 16 + cq) * 8);
      f32x4 z = {0.f, 0.f, 0.f, 0.f};
      z = __builtin_amdgcn_mfma_f32_16x16x32_f16(kf0, qf0, z, 0, 0, 0);
      z = __builtin_amdgcn_mfma_f32_16x16x32_f16(kf1, qf1, z, 0, 0, 0);
      st[f] = z + psX[f];
    }
    __builtin_amdgcn_s_setprio(0);
    float tm = -1e30f;
#pragma unroll
    for (int f = 0; f < 4; ++f)
#pragma unroll
      for (int r = 0; r < 4; ++r) tm = fmaxf(tm, st[f][r]);
    tm = fmaxf(tm, __shfl_xor(tm, 16));
    tm = fmaxf(tm, __shfl_xor(tm, 32));
    // T13 defer-rescale: only rescale when some row's max grew past THR=8.
    if (!__all(tm <= m_run + 8.f)) {
      const float m_new = fmaxf(m_run, tm);
      const float corr = __expf(m_run - m_new);
      l_run *= corr;
#pragma unroll
      for (int df = 0; df < 4; ++df) acc[df] *= corr;
      m_run = m_new;
    }
    float ls = 0.f;
    f16x4 pf[4];
#pragma unroll
    for (int f = 0; f < 4; ++f)
#pragma unroll
      for (int r = 0; r < 4; ++r) {
        float p = __expf(st[f][r] - m_run);
        ls += p;
        pf[f][r] = (f16)p;
      }
    ls += __shfl_xor(ls, 16);
    ls += __shfl_xor(ls, 32);
    l_run += ls;
    __builtin_amdgcn_s_setprio(1);
#pragma unroll
    for (int f = 0; f < 4; ++f)
#pragma unroll
      for (int df = 0; df < 4; ++df) {
        f16x4 vf = *reinterpret_cast<const f16x4*>(
            Vsb + ((f * 2 + (grp >> 1)) * 64 + df * 16 + cq) * 8 + (grp & 1) * 4);
        acc[df] = __builtin_amdgcn_mfma_f32_16x16x16f16(vf, pf[f], acc[df], 0, 0, 0);
      }
    __builtin_amdgcn_s_setprio(0);
  };

  // prologue: G-2 = {stage(0), pos(0)}, G-1 = {stage(1)}
  stageKV(Ks0, Vs0, 0);
  loadpos(psA, 0);
  asm volatile("" ::: "memory");
  stageKV(Ks1, Vs1, 64);
  asm volatile("" ::: "memory");

  // Tile t: stage->(t+2)%3 buffer, pos->ps[(t+1)&1]; compute (t%3, ps[t&1]).
  // vmcnt: t=0 ->12 (G-1 only 4 ops), 1..13 ->16, 14 ->12, 15 ->4.
#define TILE_STEP(T, KC, VC, KN, VN, PSC, PSN, VM)                        \
  {                                                                       \
    if ((T) + 2 < 16) stageKV(KN, VN, ((T) + 2) * 64);                    \
    if ((T) + 1 < 16) loadpos(PSN, ((T) + 1) * 64);                       \
    asm volatile("" ::: "memory");                                        \
    asm volatile("s_waitcnt vmcnt(" #VM ")" ::: "memory");                \
    __builtin_amdgcn_s_barrier();                                         \
    compute(KC, VC, PSC);                                                 \
    if ((T) < 15) __builtin_amdgcn_s_barrier();                           \
  }

  TILE_STEP(0,  Ks0, Vs0, Ks2, Vs2, psA, psB, 12)
  TILE_STEP(1,  Ks1, Vs1, Ks0, Vs0, psB, psA, 16)
  TILE_STEP(2,  Ks2, Vs2, Ks1, Vs1, psA, psB, 16)
  TILE_STEP(3,  Ks0, Vs0, Ks2, Vs2, psB, psA, 16)
  TILE_STEP(4,  Ks1, Vs1, Ks0, Vs0, psA, psB, 16)
  TILE_STEP(5,  Ks2, Vs2, Ks1, Vs1, psB, psA, 16)
  TILE_STEP(6,  Ks0, Vs0, Ks2, Vs2, psA, psB, 16)
  TILE_STEP(7,  Ks1, Vs1, Ks0, Vs0, psB, psA, 16)
  TILE_STEP(8,  Ks2, Vs2, Ks1, Vs1, psA, psB, 16)
  TILE_STEP(9,  Ks0, Vs0, Ks2, Vs2, psB, psA, 16)
  TILE_STEP(10, Ks1, Vs1, Ks0, Vs0, psA, psB, 16)
  TILE_STEP(11, Ks2, Vs2, Ks1, Vs1, psB, psA, 16)
  TILE_STEP(12, Ks0, Vs0, Ks2, Vs2, psA, psB, 16)
  TILE_STEP(13, Ks1, Vs1, Ks0, Vs0, psB, psA, 16)
  TILE_STEP(14, Ks2, Vs2, Ks1, Vs1, psA, psB, 12)
  TILE_STEP(15, Ks0, Vs0, Ks2, Vs2, psB, psA, 4)
#undef TILE_STEP

  const float sc = mask[b * 1024 + q] / l_run;
  f16* ob = attO + ((size_t)b * 1024 + q) * 768 + h * 64;
#pragma unroll
  for (int df = 0; df < 4; ++df) {
    f16x4 o;
#pragma unroll
    for (int r = 0; r < 4; ++r) o[r] = (f16)(acc[df][r] * sc);
    *reinterpret_cast<f16x4*>(ob + df * 16 + grp * 4) = o;
  }
}

extern "C" void kernel_launch(void* const* d_in, const int* in_sizes, int n_in,
                              void* d_out, int out_size, void* d_ws, size_t ws_size,
                              hipStream_t stream) {
  const float* Xq   = (const float*)d_in[0];
  const float* Xkv  = (const float*)d_in[1];
  const float* mask = (const float*)d_in[2];
  const float* Wq   = (const float*)d_in[3];
  const float* bq   = (const float*)d_in[4];
  const float* Wkv  = (const float*)d_in[5];
  const float* bkv  = (const float*)d_in[6];
  const float* Wp   = (const float*)d_in[7];
  const float* bp   = (const float*)d_in[8];
  const float* pos  = (const float*)d_in[9];
  float* out = (float*)d_out;
  char* ws = (char*)d_ws;
  if (ws_size < 42467328) return;  // need ~42.5 MB scratch

  f16* Xq_h  = (f16*)(ws + 0);         // 4096*768
  f16* Xkv_h = (f16*)(ws + 6291456);   // 4096*768
  f16* WqT   = (f16*)(ws + 12582912);  // 768*768
  f16* WkvT  = (f16*)(ws + 13762560);  // 1536*768
  f16* WpT   = (f16*)(ws + 16121856);  // 768*768
  f16* Qb    = (f16*)(ws + 17301504);  // (B,NH,LQ,HD)
  f16* Kb    = (f16*)(ws + 23592960);  // (B,NH,LKV,HD)
  f16* VTb   = (f16*)(ws + 29884416);  // (B,NH,HD,LKV)
  f16* attO  = (f16*)(ws + 36175872);  // (B,LQ,EMBED)

  prep_kernel<<<7296, 256, 0, stream>>>(Xq, Xkv, Wq, Wkv, Wp, Xq_h, Xkv_h, WqT,
                                        WkvT, WpT);
  gemm_qkv_kernel<<<576, 256, 0, stream>>>(Xq_h, WqT, bq, Qb, Xkv_h, WkvT, bkv,
                                           Kb, VTb);
  attn_kernel<<<768, 256, 0, stream>>>(Qb, Kb, VTb, pos, mask, attO);
  gemm_out_kernel<<<192, 256, 0, stream>>>(attO, WpT, bp, out);
}

// Round 7
// 136.669 us; speedup vs baseline: 1.2951x; 1.0054x over previous
//
#include <hip/hip_runtime.h>
#include <hip/hip_fp16.h>
#include <stdint.h>

// MaskCrossAttention: B=4, LQ=LKV=1024, C=EMBED=768, NH=12, HD=64, SCALE=0.125
// Round 6: attn TLP fix — 512-thread blocks, 2 teams of 4 waves; team k owns
// kv half k (intra-block flash split), KVBLK=32, 3-buffer LDS + counted vmcnt
// per team, in-LDS online-softmax combine at the end. 24 waves/CU (was 12).
// Launches: prep -> gemm_qkv -> attn -> gemm_out.

typedef _Float16 f16;
typedef __attribute__((ext_vector_type(8))) _Float16 f16x8;
typedef __attribute__((ext_vector_type(4))) _Float16 f16x4;
typedef __attribute__((ext_vector_type(4))) float f32x4;

__device__ __forceinline__ void gload16(const void* g, void* l) {
  __builtin_amdgcn_global_load_lds(
      (__attribute__((address_space(1))) void*)(uintptr_t)g,
      (__attribute__((address_space(3))) void*)(uint32_t)(uintptr_t)l,
      16, 0, 0);
}

// ---------------- fused prep: cvt Xq, cvt Xkv, transpose Wq/Wkv/Wp ----------
__device__ __forceinline__ void cvt4_job(const float* __restrict__ in,
                                         f16* __restrict__ out, int i) {
  float4 v = reinterpret_cast<const float4*>(in)[i];
  f16x4 o = {(f16)v.x, (f16)v.y, (f16)v.z, (f16)v.w};
  reinterpret_cast<f16x4*>(out)[i] = o;
}
__device__ __forceinline__ void transw_job(const float* __restrict__ W,
                                           f16* __restrict__ Wt, int N, int bid,
                                           int tid) {
  int kcb = bid % 96;  // 96 = 768/8
  int n = (bid / 96) * 256 + tid;
  int k0 = kcb * 8;
  f16x8 o;
#pragma unroll
  for (int j = 0; j < 8; ++j) o[j] = (f16)W[(size_t)(k0 + j) * N + n];
  *reinterpret_cast<f16x8*>(Wt + (size_t)n * 768 + k0) = o;
}
__global__ __launch_bounds__(256) void prep_kernel(
    const float* __restrict__ Xq, const float* __restrict__ Xkv,
    const float* __restrict__ Wq, const float* __restrict__ Wkv,
    const float* __restrict__ Wp, f16* __restrict__ Xq_h,
    f16* __restrict__ Xkv_h, f16* __restrict__ WqT, f16* __restrict__ WkvT,
    f16* __restrict__ WpT) {
  const int bid = blockIdx.x, tid = threadIdx.x;
  if (bid < 3072) cvt4_job(Xq, Xq_h, bid * 256 + tid);
  else if (bid < 6144) cvt4_job(Xkv, Xkv_h, (bid - 3072) * 256 + tid);
  else if (bid < 6432) transw_job(Wq, WqT, 768, bid - 6144, tid);
  else if (bid < 7008) transw_job(Wkv, WkvT, 1536, bid - 6432, tid);
  else transw_job(Wp, WpT, 768, bid - 7008, tid);
}

// ---------------- GEMM body: C = A(4096x768) * Bt(N x 768)^T + bias ---------
template <int NDIM, int EPI>
__device__ __forceinline__ void gemm_body(int bid, f16* As, f16* Bs,
                                          const f16* __restrict__ A,
                                          const f16* __restrict__ Bt,
                                          const float* __restrict__ bias,
                                          void* __restrict__ out0,
                                          void* __restrict__ out1) {
  constexpr int KD = 768;
  const int t = threadIdx.x;
  const int lane = t & 63, wid = t >> 6;
  const int bm = bid / (NDIM / 128), bn = bid % (NDIM / 128);
  const int m0 = bm * 128, n0 = bn * 128;
  const int wm = wid >> 1, wn = wid & 1;
  const int cr = lane & 15, grp = lane >> 4;
  f32x4 acc[4][4] = {};
  for (int k0 = 0; k0 < KD; k0 += 32) {
    __syncthreads();
#pragma unroll
    for (int it = 0; it < 2; ++it) {
      int ia = it * 256 + wid * 64 + lane;
      int kc = ia >> 7, row = ia & 127;
      gload16(A + (size_t)(m0 + row) * KD + k0 + kc * 8,
              As + (it * 256 + wid * 64) * 8);
      gload16(Bt + (size_t)(n0 + row) * KD + k0 + kc * 8,
              Bs + (it * 256 + wid * 64) * 8);
    }
    __syncthreads();
    f16x8 af[4], bf[4];
#pragma unroll
    for (int mf = 0; mf < 4; ++mf)
      af[mf] = *reinterpret_cast<const f16x8*>(As + (grp * 128 + wm * 64 + mf * 16 + cr) * 8);
#pragma unroll
    for (int nf = 0; nf < 4; ++nf)
      bf[nf] = *reinterpret_cast<const f16x8*>(Bs + (grp * 128 + wn * 64 + nf * 16 + cr) * 8);
#pragma unroll
    for (int mf = 0; mf < 4; ++mf)
#pragma unroll
      for (int nf = 0; nf < 4; ++nf)
        acc[mf][nf] = __builtin_amdgcn_mfma_f32_16x16x32_f16(af[mf], bf[nf], acc[mf][nf], 0, 0, 0);
  }
#pragma unroll
  for (int mf = 0; mf < 4; ++mf) {
    int m = m0 + wm * 64 + mf * 16 + grp * 4;  // +r per reg
    int b = m >> 10, lrow = m & 1023;
#pragma unroll
    for (int nf = 0; nf < 4; ++nf) {
      int n = n0 + wn * 64 + nf * 16 + cr;
      float bv = bias[n];
      f32x4 v = acc[mf][nf];
      if constexpr (EPI == 0) {
        int h = n >> 6, d = n & 63;
        f16* dst = (f16*)out0 + (((size_t)b * 12 + h) * 1024 + lrow) * 64 + d;
#pragma unroll
        for (int r = 0; r < 4; ++r) dst[(size_t)r * 64] = (f16)((v[r] + bv) * 0.125f);
      } else if constexpr (EPI == 1) {
        if (n < 768) {
          int h = n >> 6, d = n & 63;
          f16* dst = (f16*)out0 + (((size_t)b * 12 + h) * 1024 + lrow) * 64 + d;
#pragma unroll
          for (int r = 0; r < 4; ++r) dst[(size_t)r * 64] = (f16)(v[r] + bv);
        } else {
          int n2 = n - 768;
          int h = n2 >> 6, d = n2 & 63;
          f16x4 o;
#pragma unroll
          for (int r = 0; r < 4; ++r) o[r] = (f16)(v[r] + bv);
          *reinterpret_cast<f16x4*>((f16*)out1 + (((size_t)b * 12 + h) * 64 + d) * 1024 + lrow) = o;
        }
      } else {
        float* dst = (float*)out0 + (size_t)m * 768 + n;
#pragma unroll
        for (int r = 0; r < 4; ++r) dst[(size_t)r * 768] = v[r] + bv;
      }
    }
  }
}

__global__ __launch_bounds__(256) void gemm_qkv_kernel(
    const f16* __restrict__ Xq_h, const f16* __restrict__ WqT,
    const float* __restrict__ bq, f16* __restrict__ Qb,
    const f16* __restrict__ Xkv_h, const f16* __restrict__ WkvT,
    const float* __restrict__ bkv, f16* __restrict__ Kb, f16* __restrict__ VTb) {
  __shared__ f16 As[4096];
  __shared__ f16 Bs[4096];
  const int swz = (blockIdx.x % 8) * 72 + blockIdx.x / 8;  // 576 = 8*72
  if (swz < 192)
    gemm_body<768, 0>(swz, As, Bs, Xq_h, WqT, bq, Qb, nullptr);
  else
    gemm_body<1536, 1>(swz - 192, As, Bs, Xkv_h, WkvT, bkv, Kb, VTb);
}

__global__ __launch_bounds__(256) void gemm_out_kernel(
    const f16* __restrict__ attO, const f16* __restrict__ WpT,
    const float* __restrict__ bp, float* __restrict__ out) {
  __shared__ f16 As[4096];
  __shared__ f16 Bs[4096];
  const int swz = (blockIdx.x % 8) * 24 + blockIdx.x / 8;  // 192 = 8*24
  gemm_body<768, 2>(swz, As, Bs, attO, WpT, bp, out, nullptr);
}

// ---------------- fused flash attention: 2-team kv-split -------------------
// 768 blocks x 512 threads. team = wid>>2 owns kv half [team*512, +512),
// 16 tiles of KVBLK=32, 3-buffer LDS + counted vmcnt per team (shared
// barriers — both teams run the identical schedule). End: in-LDS combine.
// Block remap keeps 4 batches of one (h,qtile) on the same XCD (pos in L2).
__global__ __launch_bounds__(512, 6) void attn_kernel(
    const f16* __restrict__ Q, const f16* __restrict__ K,
    const f16* __restrict__ VT, const float* __restrict__ pos,
    const float* __restrict__ mask, f16* __restrict__ attO) {
  __shared__ f16 SH[2][6][2048];  // [team][K0,K1,K2,V0,V1,V2][32kv x 64d]
  const int t = threadIdx.x;
  const int lane = t & 63, wid = t >> 6;
  const int team = wid >> 2, tw = wid & 3, tt = t & 255;
  const int xcd = blockIdx.x & 7;
  const int j = blockIdx.x >> 3;            // 0..95
  const int gidx = xcd * 24 + (j >> 2);     // 0..191 = h*16 + qtile
  const int b = j & 3;
  const int h = gidx >> 4;
  const int qt = gidx & 15;
  const int bh = b * 12 + h;
  const int cq = lane & 15, grp = lane >> 4;
  const int q = qt * 64 + tw * 16 + cq;
  const f16* Qp = Q + ((size_t)bh * 1024 + q) * 64 + grp * 8;
  const f16x8 qf0 = *reinterpret_cast<const f16x8*>(Qp);
  const f16x8 qf1 = *reinterpret_cast<const f16x8*>(Qp + 32);
  const int kvbase = team * 512;
  const f16* Kb = K + (size_t)bh * 65536;
  const f16* Vb = VT + (size_t)bh * 65536;
  const float* pb = pos + ((size_t)h * 1024 + q) * 1024 + kvbase;

  f16* k0 = SH[team][0]; f16* k1 = SH[team][1]; f16* k2 = SH[team][2];
  f16* v0 = SH[team][3]; f16* v1 = SH[team][4]; f16* v2 = SH[team][5];

  float m_run = -1e30f, l_run = 0.f;
  f32x4 acc[4] = {};  // O^T partial: acc[df][r] -> d = df*16 + grp*4 + r
  f32x4 psA[2], psB[2];

  const int sdc = tt >> 5, skv = tt & 31;  // K stage: [dc(8)][kv(32)][8]
  const int shi = tt >> 6, slo = tt & 63;  // V stage: [kc8(4)][d(64)][8]
  auto stageKV = [&](f16* Ksb, f16* Vsb, int kv0) {  // kv0 local to team half
    gload16(Kb + (size_t)(kvbase + kv0 + skv) * 64 + sdc * 8, Ksb + tt * 8);
    gload16(Vb + (size_t)slo * 1024 + kvbase + kv0 + shi * 8, Vsb + tt * 8);
  };
  auto loadpos = [&](f32x4* psX, int kv0) {
#pragma unroll
    for (int f = 0; f < 2; ++f)
      psX[f] = *reinterpret_cast<const f32x4*>(pb + kv0 + f * 16 + grp * 4);
  };
  auto compute = [&](const f16* Ksb, const f16* Vsb, const f32x4* psX) {
    f32x4 st[2];
    __builtin_amdgcn_s_setprio(1);
#pragma unroll
    for (int f = 0; f < 2; ++f) {
      f16x8 kf0 = *reinterpret_cast<const f16x8*>(Ksb + (grp * 32 + f * 16 + cq) * 8);
      f16x8 kf1 = *reinterpret_cast<const f16x8*>(Ksb + ((4 + grp) * 32 + f * 16 + cq) * 8);
      f32x4 z = {0.f, 0.f, 0.f, 0.f};
      z = __builtin_amdgcn_mfma_f32_16x16x32_f16(kf0, qf0, z, 0, 0, 0);
      z = __builtin_amdgcn_mfma_f32_16x16x32_f16(kf1, qf1, z, 0, 0, 0);
      st[f] = z + psX[f];
    }
    __builtin_amdgcn_s_setprio(0);
    float tm = -1e30f;
#pragma unroll
    for (int f = 0; f < 2; ++f)
#pragma unroll
      for (int r = 0; r < 4; ++r) tm = fmaxf(tm, st[f][r]);
    tm = fmaxf(tm, __shfl_xor(tm, 16));
    tm = fmaxf(tm, __shfl_xor(tm, 32));
    if (!__all(tm <= m_run + 8.f)) {  // T13 defer-rescale
      const float m_new = fmaxf(m_run, tm);
      const float corr = __expf(m_run - m_new);
      l_run *= corr;
#pragma unroll
      for (int df = 0; df < 4; ++df) acc[df] *= corr;
      m_run = m_new;
    }
    float ls = 0.f;
    f16x4 pf[2];
#pragma unroll
    for (int f = 0; f < 2; ++f)
#pragma unroll
      for (int r = 0; r < 4; ++r) {
        float p = __expf(st[f][r] - m_run);
        ls += p;
        pf[f][r] = (f16)p;
      }
    ls += __shfl_xor(ls, 16);
    ls += __shfl_xor(ls, 32);
    l_run += ls;
    __builtin_amdgcn_s_setprio(1);
#pragma unroll
    for (int f = 0; f < 2; ++f)
#pragma unroll
      for (int df = 0; df < 4; ++df) {
        f16x4 vf = *reinterpret_cast<const f16x4*>(
            Vsb + ((f * 2 + (grp >> 1)) * 64 + df * 16 + cq) * 8 + (grp & 1) * 4);
        acc[df] = __builtin_amdgcn_mfma_f32_16x16x16f16(vf, pf[f], acc[df], 0, 0, 0);
      }
    __builtin_amdgcn_s_setprio(0);
  };

  // prologue: {stage(0), pos(0)} then {stage(1)}
  stageKV(k0, v0, 0);
  loadpos(psA, 0);
  asm volatile("" ::: "memory");
  stageKV(k1, v1, 32);
  asm volatile("" ::: "memory");

  // Tile t: issue {stage(t+2), pos(t+1)}, wait stage(t), barrier, compute(t).
  // Per-thread 4 vmem ops/step; vmcnt: t0=8, t1=8, t2..13=10, t14=8, t15=4.
#define TILE_STEP(T, KC, VC, KN, VN, PSC, PSN, VM)                        \
  {                                                                       \
    if ((T) + 2 < 16) stageKV(KN, VN, ((T) + 2) * 32);                    \
    if ((T) + 1 < 16) loadpos(PSN, ((T) + 1) * 32);                       \
    asm volatile("" ::: "memory");                                        \
    asm volatile("s_waitcnt vmcnt(" #VM ")" ::: "memory");                \
    __builtin_amdgcn_s_barrier();                                         \
    compute(KC, VC, PSC);                                                 \
    if ((T) < 15) __builtin_amdgcn_s_barrier();                           \
  }

  TILE_STEP(0,  k0, v0, k2, v2, psA, psB, 8)
  TILE_STEP(1,  k1, v1, k0, v0, psB, psA, 8)
  TILE_STEP(2,  k2, v2, k1, v1, psA, psB, 10)
  TILE_STEP(3,  k0, v0, k2, v2, psB, psA, 10)
  TILE_STEP(4,  k1, v1, k0, v0, psA, psB, 10)
  TILE_STEP(5,  k2, v2, k1, v1, psB, psA, 10)
  TILE_STEP(6,  k0, v0, k2, v2, psA, psB, 10)
  TILE_STEP(7,  k1, v1, k0, v0, psB, psA, 10)
  TILE_STEP(8,  k2, v2, k1, v1, psA, psB, 10)
  TILE_STEP(9,  k0, v0, k2, v2, psB, psA, 10)
  TILE_STEP(10, k1, v1, k0, v0, psA, psB, 10)
  TILE_STEP(11, k2, v2, k1, v1, psB, psA, 10)
  TILE_STEP(12, k0, v0, k2, v2, psA, psB, 10)
  TILE_STEP(13, k1, v1, k0, v0, psB, psA, 10)
  TILE_STEP(14, k2, v2, k1, v1, psA, psB, 8)
  TILE_STEP(15, k0, v0, k2, v2, psB, psA, 4)
#undef TILE_STEP

  // ---- combine the two kv-half partials (online-softmax merge) ----
  __syncthreads();
  float* cmb = (float*)&SH[1][0][0];  // 256 x 19 f32 = 19456 B (<= 24576)
  const int ci = (tw * 64 + lane) * 19;
  if (team == 1) {
    cmb[ci] = m_run;
    cmb[ci + 1] = l_run;
#pragma unroll
    for (int df = 0; df < 4; ++df)
#pragma unroll
      for (int r = 0; r < 4; ++r) cmb[ci + 2 + df * 4 + r] = acc[df][r];
  }
  __syncthreads();
  if (team == 0) {
    const float m1 = cmb[ci], l1 = cmb[ci + 1];
    const float mm = fmaxf(m_run, m1);
    const float a0 = __expf(m_run - mm), a1 = __expf(m1 - mm);
    const float sc = mask[b * 1024 + q] / (l_run * a0 + l1 * a1);
    f16* ob = attO + ((size_t)b * 1024 + q) * 768 + h * 64;
#pragma unroll
    for (int df = 0; df < 4; ++df) {
      f16x4 o;
#pragma unroll
      for (int r = 0; r < 4; ++r)
        o[r] = (f16)((acc[df][r] * a0 + cmb[ci + 2 + df * 4 + r] * a1) * sc);
      *reinterpret_cast<f16x4*>(ob + df * 16 + grp * 4) = o;
    }
  }
}

extern "C" void kernel_launch(void* const* d_in, const int* in_sizes, int n_in,
                              void* d_out, int out_size, void* d_ws, size_t ws_size,
                              hipStream_t stream) {
  const float* Xq   = (const float*)d_in[0];
  const float* Xkv  = (const float*)d_in[1];
  const float* mask = (const float*)d_in[2];
  const float* Wq   = (const float*)d_in[3];
  const float* bq   = (const float*)d_in[4];
  const float* Wkv  = (const float*)d_in[5];
  const float* bkv  = (const float*)d_in[6];
  const float* Wp   = (const float*)d_in[7];
  const float* bp   = (const float*)d_in[8];
  const float* pos  = (const float*)d_in[9];
  float* out = (float*)d_out;
  char* ws = (char*)d_ws;
  if (ws_size < 42467328) return;  // need ~42.5 MB scratch

  f16* Xq_h  = (f16*)(ws + 0);         // 4096*768
  f16* Xkv_h = (f16*)(ws + 6291456);   // 4096*768
  f16* WqT   = (f16*)(ws + 12582912);  // 768*768
  f16* WkvT  = (f16*)(ws + 13762560);  // 1536*768
  f16* WpT   = (f16*)(ws + 16121856);  // 768*768
  f16* Qb    = (f16*)(ws + 17301504);  // (B,NH,LQ,HD)
  f16* Kb    = (f16*)(ws + 23592960);  // (B,NH,LKV,HD)
  f16* VTb   = (f16*)(ws + 29884416);  // (B,NH,HD,LKV)
  f16* attO  = (f16*)(ws + 36175872);  // (B,LQ,EMBED)

  prep_kernel<<<7296, 256, 0, stream>>>(Xq, Xkv, Wq, Wkv, Wp, Xq_h, Xkv_h, WqT,
                                        WkvT, WpT);
  gemm_qkv_kernel<<<576, 256, 0, stream>>>(Xq_h, WqT, bq, Qb, Xkv_h, WkvT, bkv,
                                           Kb, VTb);
  attn_kernel<<<768, 512, 0, stream>>>(Qb, Kb, VTb, pos, mask, attO);
  gemm_out_kernel<<<192, 256, 0, stream>>>(attO, WpT, bp, out);
}